// Round 5
// baseline (2304.372 us; speedup 1.0000x reference)
//
#include <hip/hip_runtime.h>
#include <hip/hip_bf16.h>

namespace {
constexpr int B = 8;
constexpr int N = 4096;
constexpr int KNN = 20;
constexpr int NSEG = 4;
constexpr int SEGLEN = N / NSEG;   // 1024
constexpr int CAP = 24;
constexpr int SLOTS = NSEG * CAP;  // 96
constexpr int TS = 128;            // tbuf row stride (only [0:64) used for prefix)

// workspace layout (bytes) — peak ~63.0 MB
constexpr size_t OFF_IDX  = 0;                          // int [B][N][KNN]
constexpr size_t SZ_IDX   = (size_t)B * N * KNN * 4;
constexpr size_t OFF_T    = OFF_IDX + SZ_IDX;           // float [B][N][128]
constexpr size_t SZ_T     = (size_t)B * N * TS * 4;
constexpr size_t OFF_CAT  = OFF_T + SZ_T;               // float [B][N][320]
constexpr size_t SZ_CAT   = (size_t)B * N * 320 * 4;
constexpr size_t OFF_PV   = OFF_CAT + SZ_CAT;           // float [B][1024][32]
constexpr size_t SZ_PV    = (size_t)B * 1024 * 32 * 4;
constexpr size_t OFF_PI   = OFF_PV + SZ_PV;             // int   [B][1024][32]
constexpr size_t OFF_GLOB = OFF_PI + SZ_PV;             // float [B][1024]
constexpr size_t OFF_H    = OFF_GLOB + (size_t)B * 1024 * 4;  // float [B][512]
// knn scratch overlaid on T + head of CAT (dead once merge completes):
constexpr size_t OFF_LD   = OFF_T;                      // float [B*N][SLOTS]
constexpr size_t SZ_LD    = (size_t)B * N * SLOTS * 4;
constexpr size_t OFF_LJ   = OFF_LD + SZ_LD;             // int   [B*N][SLOTS]
constexpr size_t OFF_CNT  = OFF_LJ + SZ_LD;             // int   [B*N][NSEG]
}  // namespace

// Non-contractable fp32 ops: bit-exact match to np's mul-then-add serial loops.
// (-ffp-contract=fast-honor-pragmas honors the block pragma -> no fma fusion.)
__device__ __forceinline__ float mulrn(float a, float b) {
#pragma clang fp contract(off)
  return a * b;
}
__device__ __forceinline__ float addrn(float a, float b) {
#pragma clang fp contract(off)
  return a + b;
}
__device__ __forceinline__ float subrn(float a, float b) {
#pragma clang fp contract(off)
  return a - b;
}

// ---------------------------------------------------------------------------
// kNN: per-thread scan of one row-segment keeping sorted top-20 distances,
// then recovery pass collects (d, j) with d <= theta in ascending-j order.
// Distance math matches np association order bit-for-bit.
// ---------------------------------------------------------------------------
__global__ __launch_bounds__(256) void knn_scan(
    const float* __restrict__ pts,
    float* __restrict__ listd, int* __restrict__ listj, int* __restrict__ counts) {
  __shared__ float4 sp[N];  // 64 KB: (x, y, z, sq)
  const int b = blockIdx.y;
  const int tid = threadIdx.x;
  const float* px = pts + (size_t)b * 3 * N;
  for (int i = tid; i < N; i += 256) {
    const float x = px[i];
    const float y = px[N + i];
    const float z = px[2 * N + i];
    const float sq = addrn(addrn(mulrn(x, x), mulrn(y, y)), mulrn(z, z));
    sp[i] = make_float4(x, y, z, sq);
  }
  __syncthreads();
  const int row = blockIdx.x * 64 + (tid & 63);
  const int seg = tid >> 6;
  const float4 q = sp[row];
  float ds[KNN];
#pragma unroll
  for (int t = 0; t < KNN; ++t) ds[t] = 3.0e38f;
  const int j0 = seg * SEGLEN;
#pragma unroll 4
  for (int jj = 0; jj < SEGLEN; ++jj) {
    const int j = j0 + jj;
    const float4 c = sp[j];
    float t0 = mulrn(q.x, c.x);
    t0 = addrn(t0, mulrn(q.y, c.y));
    t0 = addrn(t0, mulrn(q.z, c.z));
    const float d = subrn(addrn(q.w, c.w), mulrn(2.0f, t0));
    if (d < ds[KNN - 1]) {
      float cur = d;
#pragma unroll
      for (int t = 0; t < KNN; ++t) {
        const float lo = fminf(cur, ds[t]);
        cur = fmaxf(cur, ds[t]);
        ds[t] = lo;
      }
    }
  }
  const float th = ds[KNN - 1];
  const int rbase = (b * N + row) * NSEG + seg;
  float* ld = listd + (size_t)(b * N + row) * SLOTS + seg * CAP;
  int* lj = listj + (size_t)(b * N + row) * SLOTS + seg * CAP;
  int cnt = 0;
#pragma unroll 4
  for (int jj = 0; jj < SEGLEN; ++jj) {
    const int j = j0 + jj;
    const float4 c = sp[j];
    float t0 = mulrn(q.x, c.x);
    t0 = addrn(t0, mulrn(q.y, c.y));
    t0 = addrn(t0, mulrn(q.z, c.z));
    const float d = subrn(addrn(q.w, c.w), mulrn(2.0f, t0));
    if (d <= th && cnt < CAP) {
      ld[cnt] = d;
      lj[cnt] = j;
      ++cnt;
    }
  }
  counts[rbase] = cnt;
}

// Merge: per row, select 20 lexicographically-smallest (dist, j) from <=96
// candidates via monotone uint64 keys.
__global__ __launch_bounds__(64) void knn_merge(
    const float* __restrict__ listd, const int* __restrict__ listj,
    const int* __restrict__ counts, int* __restrict__ idxout) {
  __shared__ unsigned long long keys[64][SLOTS + 1];  // 49,664 B
  const int r0 = blockIdx.x * 64;
  const int t = threadIdx.x;
  for (int i = t; i < 64 * SLOTS; i += 64) {
    const int rr = i / SLOTS;
    const int sl = i % SLOTS;
    const int seg = sl / CAP;
    const int e = sl % CAP;
    const int row = r0 + rr;
    unsigned long long key = 0xFFFFFFFE00000000ULL | (unsigned)row;  // fallback: self
    if (e < counts[row * NSEG + seg]) {
      const float d = listd[(size_t)row * SLOTS + sl];
      unsigned ub = __float_as_uint(d);
      ub ^= (ub & 0x80000000u) ? 0xFFFFFFFFu : 0x80000000u;
      key = ((unsigned long long)ub << 32) | (unsigned)listj[(size_t)row * SLOTS + sl];
    }
    keys[rr][sl] = key;
  }
  __syncthreads();
  int* outp = idxout + (size_t)(r0 + t) * KNN;
  for (int sel = 0; sel < KNN; ++sel) {
    unsigned long long best = ~0ULL;
    int bs = 0;
    for (int sl = 0; sl < SLOTS; ++sl) {
      const unsigned long long k2 = keys[t][sl];
      if (k2 < best) { best = k2; bs = sl; }
    }
    keys[t][bs] = ~0ULL;
    outp[sel] = (int)(best & 0xFFFFFFFFu);
  }
}

// ---------------------------------------------------------------------------
// EdgeConv, BIT-EXACT serial semantics. np does, per (o, n, k):
//   y = 0; for c in 0..cin-1:  y += W[o,c] * ctr[c]
//          for c in 0..cin-1:  y += W[o,cin+c] * (nb[c] - ctr[c])
// The first half depends only on (n, o): compute it once (ec_prefix) and
// CONTINUE the same serial accumulation per neighbor (exact prefix property).
// ---------------------------------------------------------------------------

// Layer 1 (cin=3): wave per point, lane = output o. No LDS needed.
__global__ __launch_bounds__(256) void ec_layer1(
    const float* __restrict__ pts, const int* __restrict__ idx,
    const float* __restrict__ w, const float* __restrict__ s,
    const float* __restrict__ bi, float* __restrict__ cat) {
  const int b = blockIdx.y;
  const int n = blockIdx.x * 4 + (threadIdx.x >> 6);
  const int o = threadIdx.x & 63;
  const float* p = pts + (size_t)b * 3 * N;
  const float xix = p[n], xiy = p[N + n], xiz = p[2 * N + n];
  const float* wr = w + o * 6;
  const float w0 = wr[0], w1 = wr[1], w2 = wr[2], w3 = wr[3], w4 = wr[4], w5 = wr[5];
  // prefix over c=0..2 (serial)
  float P = mulrn(w0, xix);
  P = addrn(P, mulrn(w1, xiy));
  P = addrn(P, mulrn(w2, xiz));
  const float so = s[o], bo = bi[o];
  const int* ip = idx + ((size_t)b * N + n) * KNN;
  float m = 0.0f;  // relu(max_k v) == max(0, max_k v)
#pragma unroll 4
  for (int k = 0; k < KNN; ++k) {
    int j = ip[k];
    if ((unsigned)j >= (unsigned)N) j = n;
    const float ex = subrn(p[j], xix);
    const float ey = subrn(p[N + j], xiy);
    const float ez = subrn(p[2 * N + j], xiz);
    float acc = addrn(P, mulrn(w3, ex));
    acc = addrn(acc, mulrn(w4, ey));
    acc = addrn(acc, mulrn(w5, ez));
    m = fmaxf(m, addrn(mulrn(so, acc), bo));
  }
  cat[((size_t)b * N + n) * 320 + o] = m;
}

// Prefix for 64-in layers: P[b][n][o] = serial sum_{c<64} W[o][c]*x[c].
// 64 threads (one wave), 16 points staged per block.
__global__ __launch_bounds__(64) void ec_prefix(
    const float* __restrict__ cat, int inoff, const float* __restrict__ w,
    float* __restrict__ tP) {
  __shared__ float xs[16][64];  // 4 KB
  const int b = blockIdx.y;
  const int n0 = blockIdx.x * 16;
  const int o = threadIdx.x;
  const float* wr = w + (size_t)o * 128;  // first half of the 128-wide row
  float wreg[64];
#pragma unroll
  for (int c = 0; c < 64; ++c) wreg[c] = wr[c];
  const float* xp = cat + ((size_t)b * N + n0) * 320 + inoff;
  for (int i = o; i < 16 * 64; i += 64) {
    const int p = i >> 6;
    const int k = i & 63;
    xs[p][k] = xp[(size_t)p * 320 + k];
  }
  __syncthreads();
  float* tp = tP + ((size_t)b * N + n0) * TS + o;
  for (int p = 0; p < 16; ++p) {
    const float2* x2 = (const float2*)(&xs[p][0]);
    float acc = mulrn(wreg[0], xs[p][0]);
    acc = addrn(acc, mulrn(wreg[1], xs[p][1]));
#pragma unroll
    for (int k2 = 1; k2 < 32; ++k2) {
      const float2 v = x2[k2];
      acc = addrn(acc, mulrn(wreg[2 * k2], v.x));
      acc = addrn(acc, mulrn(wreg[2 * k2 + 1], v.y));
    }
    tp[(size_t)p * TS] = acc;
  }
}

// Gather+accumulate for 64-in/64-out layers: wave per point, lane = output o.
// Continues the serial sum from P with W[o][64+c]*(x_j[c]-x_i[c]), c ascending.
__global__ __launch_bounds__(256) void ec_gather(
    const float* __restrict__ cat, int inoff, const float* __restrict__ tP,
    const int* __restrict__ idx, const float* __restrict__ w,
    const float* __restrict__ s, const float* __restrict__ bi,
    float* __restrict__ catout, int outoff) {
  __shared__ float ebuf[4][64];  // per-wave e vector
  const int b = blockIdx.y;
  const int wv = threadIdx.x >> 6;
  const int n = blockIdx.x * 4 + wv;
  const int o = threadIdx.x & 63;
  const float* wr = w + (size_t)o * 128 + 64;  // second half of row o
  float wreg[64];
#pragma unroll
  for (int c = 0; c < 64; ++c) wreg[c] = wr[c];
  const float* xin = cat + ((size_t)b * N + n) * 320 + inoff;
  const float xi = xin[o];  // lane o holds x_i[o]
  float* eb = &ebuf[wv][0];
  const float P = tP[((size_t)b * N + n) * TS + o];
  const float so = s[o], bo = bi[o];
  const int* ip = idx + ((size_t)b * N + n) * KNN;
  float m = 0.0f;
  for (int k = 0; k < KNN; ++k) {
    int j = ip[k];
    if ((unsigned)j >= (unsigned)N) j = n;
    const float xj = cat[((size_t)b * N + j) * 320 + inoff + o];
    eb[o] = subrn(xj, xi);  // intra-wave LDS; compiler orders via lgkmcnt
    float acc = P;
    const float4* e4 = (const float4*)eb;
#pragma unroll
    for (int c4 = 0; c4 < 16; ++c4) {
      const float4 e = e4[c4];  // broadcast read (all lanes same addr)
      acc = addrn(acc, mulrn(wreg[4 * c4 + 0], e.x));
      acc = addrn(acc, mulrn(wreg[4 * c4 + 1], e.y));
      acc = addrn(acc, mulrn(wreg[4 * c4 + 2], e.z));
      acc = addrn(acc, mulrn(wreg[4 * c4 + 3], e.w));
    }
    m = fmaxf(m, addrn(mulrn(so, acc), bo));
  }
  catout[((size_t)b * N + n) * 320 + outoff + o] = m;
}

// ---------------------------------------------------------------------------
// Local layer: loc[o][n] = relu(s*<W[o,:], cat[n,:]> + b), serial ascending c
// (single accumulator per output, mul+add, no fma -> bit-exact vs np einsum),
// fused block max/argmax with explicit first-occurrence tie-break.
// ---------------------------------------------------------------------------
__global__ __launch_bounds__(256) void local_gemm(
    const float* __restrict__ cat, const float* __restrict__ w,
    const float* __restrict__ s, const float* __restrict__ bi,
    float* __restrict__ pval, int* __restrict__ pidx) {
  constexpr int KC = 32;
  constexpr int XP = 129;
  constexpr int WP = 133;
  __shared__ float smem[KC * XP + KC * WP];  // 33,536 B
  float* xs = smem;
  float* wsd = smem + KC * XP;
  const int t = threadIdx.x;
  const int q0 = blockIdx.x * 128;
  const int ptile = blockIdx.y;
  const size_t pt0 = (size_t)ptile * 128;
  const int g = t & 15;
  const int h = t >> 4;
  float acc[8][8];
#pragma unroll
  for (int f = 0; f < 8; ++f)
#pragma unroll
    for (int e = 0; e < 8; ++e) acc[f][e] = 0.f;

  const int lk = t & 31;
  const int lp = t >> 5;
  for (int kc = 0; kc < 320; kc += KC) {
    __syncthreads();
#pragma unroll
    for (int i = 0; i < 16; ++i) {
      const int pt = lp + 8 * i;
      xs[lk * XP + pt] = cat[(pt0 + pt) * 320 + kc + lk];
    }
#pragma unroll
    for (int i = 0; i < 16; ++i) {
      const int cl = lp + 8 * i;
      wsd[lk * WP + cl] = w[(size_t)(q0 + cl) * 320 + kc + lk];
    }
    __syncthreads();
#pragma unroll
    for (int k = 0; k < KC; ++k) {
      float xf[8], wf[8];
#pragma unroll
      for (int e = 0; e < 8; ++e) xf[e] = xs[k * XP + g + 16 * e];
#pragma unroll
      for (int f = 0; f < 8; ++f) wf[f] = wsd[k * WP + h + 16 * f];
#pragma unroll
      for (int f = 0; f < 8; ++f)
#pragma unroll
        for (int e = 0; e < 8; ++e)
          acc[f][e] = addrn(acc[f][e], mulrn(wf[f], xf[e]));  // exact serial c
    }
  }
  // epilogue: relu(s*acc+b) with np's mul-then-add; per-thread argmax over its
  // 8 points (ascending point index within thread -> first occurrence).
  const int bb = ptile >> 5;
  const int blk = ptile & 31;
  float mv[8];
  int mi[8];
#pragma unroll
  for (int f = 0; f < 8; ++f) {
    const int cl = h + 16 * f;
    const float sc = s[q0 + cl];
    const float bc = bi[q0 + cl];
    mv[f] = -1.f;
    mi[f] = 0;
#pragma unroll
    for (int e = 0; e < 8; ++e) {
      const float v = fmaxf(addrn(mulrn(sc, acc[f][e]), bc), 0.f);
      if (v > mv[f]) { mv[f] = v; mi[f] = g + 16 * e; }
    }
  }
  __syncthreads();
  float* smv = smem;
  int* smi = (int*)(smem + 16 * 132);
#pragma unroll
  for (int f = 0; f < 8; ++f) {
    smv[g * 132 + h + 16 * f] = mv[f];
    smi[g * 132 + h + 16 * f] = mi[f];
  }
  __syncthreads();
  if (t < 128) {
    float best = smv[t];
    int bidx = smi[t];
    for (int gg = 1; gg < 16; ++gg) {
      const float v = smv[gg * 132 + t];
      const int vi = smi[gg * 132 + t];
      // candidates are g-interleaved: ties must resolve to SMALLEST point idx
      if (v > best || (v == best && vi < bidx)) { best = v; bidx = vi; }
    }
    const int n_l = blk * 128 + bidx;
    const size_t po = ((size_t)bb * 1024 + q0 + t) * 32 + blk;
    pval[po] = best;
    pidx[po] = n_l;
  }
}

__global__ __launch_bounds__(256) void final_reduce(
    const float* __restrict__ pval, const int* __restrict__ pidx,
    float* __restrict__ glob, float* __restrict__ oidx) {
  const int o = blockIdx.x * 256 + threadIdx.x;  // 8192 = B*1024
  const float* pv = pval + (size_t)o * 32;
  const int* pi = pidx + (size_t)o * 32;
  float best = pv[0];
  int bi = pi[0];
  for (int k = 1; k < 32; ++k) {
    const float v = pv[k];
    // tiles are ascending disjoint point ranges: strict > = first occurrence
    if (v > best) { best = v; bi = pi[k]; }
  }
  glob[o] = best;
  oidx[o] = (float)bi;
}

template <int KIN, int OUTS>
__global__ __launch_bounds__(256) void dense_wave(
    const float* __restrict__ in, const float* __restrict__ w,
    const float* __restrict__ s, const float* __restrict__ bi,
    float* __restrict__ out) {
  const int wid = (blockIdx.x * 256 + threadIdx.x) >> 6;
  const int lane = threadIdx.x & 63;
  const int b = wid / OUTS;
  const int o = wid % OUTS;
  const float* ip = in + (size_t)b * KIN;
  const float* wr = w + (size_t)o * KIN;
  float acc = 0.f;
  for (int k = lane; k < KIN; k += 64) acc = fmaf(wr[k], ip[k], acc);
#pragma unroll
  for (int off = 32; off; off >>= 1) acc += __shfl_down(acc, off);
  if (lane == 0) out[(size_t)b * OUTS + o] = fmaxf(fmaf(s[o], acc, bi[o]), 0.f);
}

extern "C" void kernel_launch(void* const* d_in, const int* in_sizes, int n_in,
                              void* d_out, int out_size, void* d_ws, size_t ws_size,
                              hipStream_t stream) {
  (void)in_sizes; (void)n_in; (void)out_size; (void)ws_size;
  const float* pts = (const float*)d_in[0];
  const float* ec_w[4] = {(const float*)d_in[1], (const float*)d_in[4],
                          (const float*)d_in[7], (const float*)d_in[10]};
  const float* ec_s[4] = {(const float*)d_in[2], (const float*)d_in[5],
                          (const float*)d_in[8], (const float*)d_in[11]};
  const float* ec_b[4] = {(const float*)d_in[3], (const float*)d_in[6],
                          (const float*)d_in[9], (const float*)d_in[12]};
  const float* local_w = (const float*)d_in[13];
  const float* local_s = (const float*)d_in[14];
  const float* local_b = (const float*)d_in[15];
  const float* g_w0 = (const float*)d_in[16];
  const float* g_s0 = (const float*)d_in[17];
  const float* g_b0 = (const float*)d_in[18];
  const float* g_w1 = (const float*)d_in[19];
  const float* g_s1 = (const float*)d_in[20];
  const float* g_b1 = (const float*)d_in[21];

  char* ws = (char*)d_ws;
  int* idxbuf = (int*)(ws + OFF_IDX);
  float* tbuf = (float*)(ws + OFF_T);
  float* cat = (float*)(ws + OFF_CAT);
  float* pv = (float*)(ws + OFF_PV);
  int* pi = (int*)(ws + OFF_PI);
  float* glob = (float*)(ws + OFF_GLOB);
  float* hbuf = (float*)(ws + OFF_H);
  float* listd = (float*)(ws + OFF_LD);
  int* listj = (int*)(ws + OFF_LJ);
  int* counts = (int*)(ws + OFF_CNT);
  float* outv = (float*)d_out;   // [8][256]  fp32
  float* oidx = outv + 2048;     // [8][1024] fp32 (indices as floats)

  knn_scan<<<dim3(64, 8), 256, 0, stream>>>(pts, listd, listj, counts);
  knn_merge<<<dim3(512), 64, 0, stream>>>(listd, listj, counts, idxbuf);

  // layer 1 (3 -> 64)
  ec_layer1<<<dim3(1024, 8), 256, 0, stream>>>(pts, idxbuf, ec_w[0], ec_s[0], ec_b[0], cat);
  // layer 2 (64 -> 64)
  ec_prefix<<<dim3(256, 8), 64, 0, stream>>>(cat, 0, ec_w[1], tbuf);
  ec_gather<<<dim3(1024, 8), 256, 0, stream>>>(cat, 0, tbuf, idxbuf, ec_w[1], ec_s[1], ec_b[1], cat, 64);
  // layer 3 (64 -> 64)
  ec_prefix<<<dim3(256, 8), 64, 0, stream>>>(cat, 64, ec_w[2], tbuf);
  ec_gather<<<dim3(1024, 8), 256, 0, stream>>>(cat, 64, tbuf, idxbuf, ec_w[2], ec_s[2], ec_b[2], cat, 128);
  // layer 4 (64 -> 128), two 64-output halves (exact: outputs independent)
  ec_prefix<<<dim3(256, 8), 64, 0, stream>>>(cat, 128, ec_w[3], tbuf);
  ec_gather<<<dim3(1024, 8), 256, 0, stream>>>(cat, 128, tbuf, idxbuf, ec_w[3], ec_s[3], ec_b[3], cat, 192);
  ec_prefix<<<dim3(256, 8), 64, 0, stream>>>(cat, 128, ec_w[3] + 64 * 128, tbuf);
  ec_gather<<<dim3(1024, 8), 256, 0, stream>>>(cat, 128, tbuf, idxbuf, ec_w[3] + 64 * 128,
                                               ec_s[3] + 64, ec_b[3] + 64, cat, 256);

  local_gemm<<<dim3(8, 256), 256, 0, stream>>>(cat, local_w, local_s, local_b, pv, pi);
  final_reduce<<<dim3(32), 256, 0, stream>>>(pv, pi, glob, oidx);
  dense_wave<1024, 512><<<dim3(1024), 256, 0, stream>>>(glob, g_w0, g_s0, g_b0, hbuf);
  dense_wave<512, 256><<<dim3(512), 256, 0, stream>>>(hbuf, g_w1, g_s1, g_b1, outv);
}

// Round 6
// 2053.870 us; speedup vs baseline: 1.1220x; 1.1220x over previous
//
#include <hip/hip_runtime.h>
#include <hip/hip_bf16.h>

namespace {
constexpr int B = 8;
constexpr int N = 4096;
constexpr int KNN = 20;
constexpr int NSEG = 4;
constexpr int SEGLEN = N / NSEG;   // 1024
constexpr int CAP = 24;
constexpr int SLOTS = NSEG * CAP;  // 96

// workspace layout (bytes)
constexpr size_t OFF_IDX  = 0;                          // int [B][N][KNN]
constexpr size_t SZ_IDX   = (size_t)B * N * KNN * 4;
constexpr size_t OFF_T    = OFF_IDX + SZ_IDX;           // knn scratch region
constexpr size_t SZ_T     = (size_t)B * N * 128 * 4;
constexpr size_t OFF_CAT  = OFF_T + SZ_T;               // float [B][N][320]
constexpr size_t SZ_CAT   = (size_t)B * N * 320 * 4;
constexpr size_t OFF_PV   = OFF_CAT + SZ_CAT;           // float [B][1024][32]
constexpr size_t SZ_PV    = (size_t)B * 1024 * 32 * 4;
constexpr size_t OFF_PI   = OFF_PV + SZ_PV;             // int   [B][1024][32]
constexpr size_t OFF_GLOB = OFF_PI + SZ_PV;             // float [B][1024]
constexpr size_t OFF_H    = OFF_GLOB + (size_t)B * 1024 * 4;  // float [B][512]
// knn scratch overlaid on T + head of CAT (dead once merge completes):
constexpr size_t OFF_LD   = OFF_T;                      // float [B*N][SLOTS]
constexpr size_t SZ_LD    = (size_t)B * N * SLOTS * 4;
constexpr size_t OFF_LJ   = OFF_LD + SZ_LD;             // int   [B*N][SLOTS]
constexpr size_t OFF_CNT  = OFF_LJ + SZ_LD;             // int   [B*N][NSEG]
}  // namespace

// Non-contractable fp32 ops: bit-exact match to np's mul-then-add serial loops.
__device__ __forceinline__ float mulrn(float a, float b) {
#pragma clang fp contract(off)
  return a * b;
}
__device__ __forceinline__ float addrn(float a, float b) {
#pragma clang fp contract(off)
  return a + b;
}
__device__ __forceinline__ float subrn(float a, float b) {
#pragma clang fp contract(off)
  return a - b;
}

// ---------------------------------------------------------------------------
// kNN: per-thread scan of one row-segment keeping sorted top-20 distances,
// then recovery pass collects (d, j) with d <= theta in ascending-j order.
// ---------------------------------------------------------------------------
__global__ __launch_bounds__(256) void knn_scan(
    const float* __restrict__ pts,
    float* __restrict__ listd, int* __restrict__ listj, int* __restrict__ counts) {
  __shared__ float4 sp[N];  // 64 KB: (x, y, z, sq)
  const int b = blockIdx.y;
  const int tid = threadIdx.x;
  const float* px = pts + (size_t)b * 3 * N;
  for (int i = tid; i < N; i += 256) {
    const float x = px[i];
    const float y = px[N + i];
    const float z = px[2 * N + i];
    const float sq = addrn(addrn(mulrn(x, x), mulrn(y, y)), mulrn(z, z));
    sp[i] = make_float4(x, y, z, sq);
  }
  __syncthreads();
  const int row = blockIdx.x * 64 + (tid & 63);
  const int seg = tid >> 6;
  const float4 q = sp[row];
  float ds[KNN];
#pragma unroll
  for (int t = 0; t < KNN; ++t) ds[t] = 3.0e38f;
  const int j0 = seg * SEGLEN;
#pragma unroll 4
  for (int jj = 0; jj < SEGLEN; ++jj) {
    const int j = j0 + jj;
    const float4 c = sp[j];
    float t0 = mulrn(q.x, c.x);
    t0 = addrn(t0, mulrn(q.y, c.y));
    t0 = addrn(t0, mulrn(q.z, c.z));
    const float d = subrn(addrn(q.w, c.w), mulrn(2.0f, t0));
    if (d < ds[KNN - 1]) {
      float cur = d;
#pragma unroll
      for (int t = 0; t < KNN; ++t) {
        const float lo = fminf(cur, ds[t]);
        cur = fmaxf(cur, ds[t]);
        ds[t] = lo;
      }
    }
  }
  const float th = ds[KNN - 1];
  const int rbase = (b * N + row) * NSEG + seg;
  float* ld = listd + (size_t)(b * N + row) * SLOTS + seg * CAP;
  int* lj = listj + (size_t)(b * N + row) * SLOTS + seg * CAP;
  int cnt = 0;
#pragma unroll 4
  for (int jj = 0; jj < SEGLEN; ++jj) {
    const int j = j0 + jj;
    const float4 c = sp[j];
    float t0 = mulrn(q.x, c.x);
    t0 = addrn(t0, mulrn(q.y, c.y));
    t0 = addrn(t0, mulrn(q.z, c.z));
    const float d = subrn(addrn(q.w, c.w), mulrn(2.0f, t0));
    if (d <= th && cnt < CAP) {
      ld[cnt] = d;
      lj[cnt] = j;
      ++cnt;
    }
  }
  counts[rbase] = cnt;
}

// Merge: per row, select 20 lexicographically-smallest (dist, j) from <=96
// candidates via monotone uint64 keys.
__global__ __launch_bounds__(64) void knn_merge(
    const float* __restrict__ listd, const int* __restrict__ listj,
    const int* __restrict__ counts, int* __restrict__ idxout) {
  __shared__ unsigned long long keys[64][SLOTS + 1];  // 49,664 B
  const int r0 = blockIdx.x * 64;
  const int t = threadIdx.x;
  for (int i = t; i < 64 * SLOTS; i += 64) {
    const int rr = i / SLOTS;
    const int sl = i % SLOTS;
    const int seg = sl / CAP;
    const int e = sl % CAP;
    const int row = r0 + rr;
    unsigned long long key = 0xFFFFFFFE00000000ULL | (unsigned)row;  // fallback: self
    if (e < counts[row * NSEG + seg]) {
      const float d = listd[(size_t)row * SLOTS + sl];
      unsigned ub = __float_as_uint(d);
      ub ^= (ub & 0x80000000u) ? 0xFFFFFFFFu : 0x80000000u;
      key = ((unsigned long long)ub << 32) | (unsigned)listj[(size_t)row * SLOTS + sl];
    }
    keys[rr][sl] = key;
  }
  __syncthreads();
  int* outp = idxout + (size_t)(r0 + t) * KNN;
  for (int sel = 0; sel < KNN; ++sel) {
    unsigned long long best = ~0ULL;
    int bs = 0;
#pragma unroll 8
    for (int sl = 0; sl < SLOTS; ++sl) {
      const unsigned long long k2 = keys[t][sl];
      if (k2 < best) { best = k2; bs = sl; }
    }
    keys[t][bs] = ~0ULL;
    outp[sel] = (int)(best & 0xFFFFFFFFu);
  }
}

// ---------------------------------------------------------------------------
// EdgeConv, BIT-EXACT serial semantics. np does, per (o, n, k):
//   y = 0; for c: y += W[o,c]*ctr[c];  for c: y += W[o,cin+c]*(nb[c]-ctr[c])
// Prefix P (first half) depends only on (n,o): computed in-kernel, then the
// SAME serial accumulation continues per neighbor (exact prefix property).
// ---------------------------------------------------------------------------

// Layer 1 (cin=3): wave per point, lane = output o.
__global__ __launch_bounds__(256) void ec_layer1(
    const float* __restrict__ pts, const int* __restrict__ idx,
    const float* __restrict__ w, const float* __restrict__ s,
    const float* __restrict__ bi, float* __restrict__ cat) {
  const int b = blockIdx.y;
  const int n = blockIdx.x * 4 + (threadIdx.x >> 6);
  const int o = threadIdx.x & 63;
  const float* p = pts + (size_t)b * 3 * N;
  const float xix = p[n], xiy = p[N + n], xiz = p[2 * N + n];
  const float* wr = w + o * 6;
  const float w0 = wr[0], w1 = wr[1], w2 = wr[2], w3 = wr[3], w4 = wr[4], w5 = wr[5];
  float P = mulrn(w0, xix);
  P = addrn(P, mulrn(w1, xiy));
  P = addrn(P, mulrn(w2, xiz));
  const float so = s[o], bo = bi[o];
  const int* ip = idx + ((size_t)b * N + n) * KNN;
  float m = 0.0f;
#pragma unroll 4
  for (int k = 0; k < KNN; ++k) {
    int j = ip[k];
    if ((unsigned)j >= (unsigned)N) j = n;
    const float ex = subrn(p[j], xix);
    const float ey = subrn(p[N + j], xiy);
    const float ez = subrn(p[2 * N + j], xiz);
    float acc = addrn(P, mulrn(w3, ex));
    acc = addrn(acc, mulrn(w4, ey));
    acc = addrn(acc, mulrn(w5, ez));
    m = fmaxf(m, addrn(mulrn(so, acc), bo));
  }
  cat[((size_t)b * N + n) * 320 + o] = m;
}

// 64-in/64-out EdgeConv layer, prefix fused. Block = 4 waves = 4 points.
// Full 128-wide W rows staged coalesced into LDS once per block.
__global__ __launch_bounds__(256) void ec_layer64(
    const float* __restrict__ cat, int inoff, const int* __restrict__ idx,
    const float* __restrict__ w, const float* __restrict__ s,
    const float* __restrict__ bi, float* __restrict__ catout, int outoff) {
  __shared__ float wst[64][130];  // 33,280 B; pad 130 -> 2-way (free) reads
  __shared__ float ebuf[4][64];
  // stage all 64 W rows (128 wide), coalesced: thread t reads w[l], l linear
  for (int l = threadIdx.x; l < 64 * 128; l += 256) {
    wst[l >> 7][l & 127] = w[l];
  }
  __syncthreads();
  const int b = blockIdx.y;
  const int wv = threadIdx.x >> 6;
  const int n = blockIdx.x * 4 + wv;
  const int o = threadIdx.x & 63;
  // second-half weights -> registers (LDS reads, 2-way free: (2o+c)%32)
  float wreg[64];
#pragma unroll
  for (int c = 0; c < 64; ++c) wreg[c] = wst[o][64 + c];
  const float xi = cat[((size_t)b * N + n) * 320 + inoff + o];
  float* eb = &ebuf[wv][0];
  const float4* e4 = (const float4*)eb;
  // prefix P = serial sum_{c<64} W[o][c] * x_i[c]; x_i staged via ebuf
  eb[o] = xi;
  float P;
  {
    const float4 v0 = e4[0];
    P = mulrn(wst[o][0], v0.x);
    P = addrn(P, mulrn(wst[o][1], v0.y));
    P = addrn(P, mulrn(wst[o][2], v0.z));
    P = addrn(P, mulrn(wst[o][3], v0.w));
#pragma unroll
    for (int c4 = 1; c4 < 16; ++c4) {
      const float4 v = e4[c4];
      P = addrn(P, mulrn(wst[o][4 * c4 + 0], v.x));
      P = addrn(P, mulrn(wst[o][4 * c4 + 1], v.y));
      P = addrn(P, mulrn(wst[o][4 * c4 + 2], v.z));
      P = addrn(P, mulrn(wst[o][4 * c4 + 3], v.w));
    }
  }
  const float so = s[o], bo = bi[o];
  const int* ip = idx + ((size_t)b * N + n) * KNN;
  float m = 0.0f;
  for (int k = 0; k < KNN; ++k) {
    int j = ip[k];
    if ((unsigned)j >= (unsigned)N) j = n;
    const float xj = cat[((size_t)b * N + j) * 320 + inoff + o];
    eb[o] = subrn(xj, xi);  // intra-wave LDS roundtrip (lgkmcnt-ordered)
    float acc = P;
#pragma unroll
    for (int c4 = 0; c4 < 16; ++c4) {
      const float4 e = e4[c4];  // broadcast read (all lanes same addr)
      acc = addrn(acc, mulrn(wreg[4 * c4 + 0], e.x));
      acc = addrn(acc, mulrn(wreg[4 * c4 + 1], e.y));
      acc = addrn(acc, mulrn(wreg[4 * c4 + 2], e.z));
      acc = addrn(acc, mulrn(wreg[4 * c4 + 3], e.w));
    }
    m = fmaxf(m, addrn(mulrn(so, acc), bo));
  }
  catout[((size_t)b * N + n) * 320 + outoff + o] = m;
}

// ---------------------------------------------------------------------------
// Local layer: loc[o][n] = relu(s*<W[o,:], cat[n,:]> + b), serial ascending c
// (single accumulator, mul+add, no fma -> bit-exact vs np), fused block
// max/argmax. Register-prefetch double-buffered staging: global latency for
// chunk k+1 hides under chunk k's compute; barriers wait only on LDS stores.
// ---------------------------------------------------------------------------
__global__ __launch_bounds__(256) void local_gemm(
    const float* __restrict__ cat, const float* __restrict__ w,
    const float* __restrict__ s, const float* __restrict__ bi,
    float* __restrict__ pval, int* __restrict__ pidx) {
  constexpr int KC = 32;
  constexpr int XP = 129;  // stride%32==1 -> conflict-free stores
  constexpr int WP = 133;  // odd stride  -> conflict-free stores
  __shared__ float smem[KC * XP + KC * WP];  // 33,536 B
  float* xs = smem;
  float* wsd = smem + KC * XP;
  const int t = threadIdx.x;
  const int q0 = blockIdx.x * 128;
  const int ptile = blockIdx.y;
  const size_t pt0 = (size_t)ptile * 128;
  const int g = t & 15;
  const int h = t >> 4;
  float acc[8][8];
#pragma unroll
  for (int f = 0; f < 8; ++f)
#pragma unroll
    for (int e = 0; e < 8; ++e) acc[f][e] = 0.f;

  const int lk = t & 31;
  const int lp = t >> 5;
  const float* catp = cat + pt0 * 320 + lk;
  const float* wp = w + (size_t)q0 * 320 + lk;
  float rx[16], rw[16];
#pragma unroll
  for (int i = 0; i < 16; ++i) rx[i] = catp[(size_t)(lp + 8 * i) * 320];
#pragma unroll
  for (int i = 0; i < 16; ++i) rw[i] = wp[(size_t)(lp + 8 * i) * 320];

  for (int kc = 0; kc < 320; kc += KC) {
#pragma unroll
    for (int i = 0; i < 16; ++i) xs[lk * XP + lp + 8 * i] = rx[i];
#pragma unroll
    for (int i = 0; i < 16; ++i) wsd[lk * WP + lp + 8 * i] = rw[i];
    __syncthreads();
    if (kc + KC < 320) {  // prefetch next chunk into registers
      const int ko = kc + KC;
#pragma unroll
      for (int i = 0; i < 16; ++i) rx[i] = catp[(size_t)(lp + 8 * i) * 320 + ko];
#pragma unroll
      for (int i = 0; i < 16; ++i) rw[i] = wp[(size_t)(lp + 8 * i) * 320 + ko];
    }
#pragma unroll
    for (int k = 0; k < KC; ++k) {
      float xf[8], wf[8];
#pragma unroll
      for (int e = 0; e < 8; ++e) xf[e] = xs[k * XP + g + 16 * e];
#pragma unroll
      for (int f = 0; f < 8; ++f) wf[f] = wsd[k * WP + h + 16 * f];
#pragma unroll
      for (int f = 0; f < 8; ++f)
#pragma unroll
        for (int e = 0; e < 8; ++e)
          acc[f][e] = addrn(acc[f][e], mulrn(wf[f], xf[e]));  // exact serial c
    }
    __syncthreads();
  }
  // epilogue: relu(s*acc+b) with np's mul-then-add; per-thread argmax over its
  // 8 points (ascending within thread -> first occurrence).
  const int bb = ptile >> 5;
  const int blk = ptile & 31;
  float mv[8];
  int mi[8];
#pragma unroll
  for (int f = 0; f < 8; ++f) {
    const int cl = h + 16 * f;
    const float sc = s[q0 + cl];
    const float bc = bi[q0 + cl];
    mv[f] = -1.f;
    mi[f] = 0;
#pragma unroll
    for (int e = 0; e < 8; ++e) {
      const float v = fmaxf(addrn(mulrn(sc, acc[f][e]), bc), 0.f);
      if (v > mv[f]) { mv[f] = v; mi[f] = g + 16 * e; }
    }
  }
  __syncthreads();
  float* smv = smem;
  int* smi = (int*)(smem + 16 * 132);
#pragma unroll
  for (int f = 0; f < 8; ++f) {
    smv[g * 132 + h + 16 * f] = mv[f];
    smi[g * 132 + h + 16 * f] = mi[f];
  }
  __syncthreads();
  if (t < 128) {
    float best = smv[t];
    int bidx = smi[t];
    for (int gg = 1; gg < 16; ++gg) {
      const float v = smv[gg * 132 + t];
      const int vi = smi[gg * 132 + t];
      // candidates g-interleaved: ties resolve to SMALLEST point idx
      if (v > best || (v == best && vi < bidx)) { best = v; bidx = vi; }
    }
    const int n_l = blk * 128 + bidx;
    const size_t po = ((size_t)bb * 1024 + q0 + t) * 32 + blk;
    pval[po] = best;
    pidx[po] = n_l;
  }
}

__global__ __launch_bounds__(256) void final_reduce(
    const float* __restrict__ pval, const int* __restrict__ pidx,
    float* __restrict__ glob, float* __restrict__ oidx) {
  const int o = blockIdx.x * 256 + threadIdx.x;  // 8192 = B*1024
  const float* pv = pval + (size_t)o * 32;
  const int* pi = pidx + (size_t)o * 32;
  float best = pv[0];
  int bi = pi[0];
  for (int k = 1; k < 32; ++k) {
    const float v = pv[k];
    // tiles are ascending disjoint point ranges: strict > = first occurrence
    if (v > best) { best = v; bi = pi[k]; }
  }
  glob[o] = best;
  oidx[o] = (float)bi;
}

template <int KIN, int OUTS>
__global__ __launch_bounds__(256) void dense_wave(
    const float* __restrict__ in, const float* __restrict__ w,
    const float* __restrict__ s, const float* __restrict__ bi,
    float* __restrict__ out) {
  const int wid = (blockIdx.x * 256 + threadIdx.x) >> 6;
  const int lane = threadIdx.x & 63;
  const int b = wid / OUTS;
  const int o = wid % OUTS;
  const float* ip = in + (size_t)b * KIN;
  const float* wr = w + (size_t)o * KIN;
  float acc = 0.f;
  for (int k = lane; k < KIN; k += 64) acc = fmaf(wr[k], ip[k], acc);
#pragma unroll
  for (int off = 32; off; off >>= 1) acc += __shfl_down(acc, off);
  if (lane == 0) out[(size_t)b * OUTS + o] = fmaxf(fmaf(s[o], acc, bi[o]), 0.f);
}

extern "C" void kernel_launch(void* const* d_in, const int* in_sizes, int n_in,
                              void* d_out, int out_size, void* d_ws, size_t ws_size,
                              hipStream_t stream) {
  (void)in_sizes; (void)n_in; (void)out_size; (void)ws_size;
  const float* pts = (const float*)d_in[0];
  const float* ec_w[4] = {(const float*)d_in[1], (const float*)d_in[4],
                          (const float*)d_in[7], (const float*)d_in[10]};
  const float* ec_s[4] = {(const float*)d_in[2], (const float*)d_in[5],
                          (const float*)d_in[8], (const float*)d_in[11]};
  const float* ec_b[4] = {(const float*)d_in[3], (const float*)d_in[6],
                          (const float*)d_in[9], (const float*)d_in[12]};
  const float* local_w = (const float*)d_in[13];
  const float* local_s = (const float*)d_in[14];
  const float* local_b = (const float*)d_in[15];
  const float* g_w0 = (const float*)d_in[16];
  const float* g_s0 = (const float*)d_in[17];
  const float* g_b0 = (const float*)d_in[18];
  const float* g_w1 = (const float*)d_in[19];
  const float* g_s1 = (const float*)d_in[20];
  const float* g_b1 = (const float*)d_in[21];

  char* ws = (char*)d_ws;
  int* idxbuf = (int*)(ws + OFF_IDX);
  float* cat = (float*)(ws + OFF_CAT);
  float* pv = (float*)(ws + OFF_PV);
  int* pi = (int*)(ws + OFF_PI);
  float* glob = (float*)(ws + OFF_GLOB);
  float* hbuf = (float*)(ws + OFF_H);
  float* listd = (float*)(ws + OFF_LD);
  int* listj = (int*)(ws + OFF_LJ);
  int* counts = (int*)(ws + OFF_CNT);
  float* outv = (float*)d_out;   // [8][256]  fp32
  float* oidx = outv + 2048;     // [8][1024] fp32 (indices as floats)

  knn_scan<<<dim3(64, 8), 256, 0, stream>>>(pts, listd, listj, counts);
  knn_merge<<<dim3(512), 64, 0, stream>>>(listd, listj, counts, idxbuf);

  // layer 1 (3 -> 64)
  ec_layer1<<<dim3(1024, 8), 256, 0, stream>>>(pts, idxbuf, ec_w[0], ec_s[0], ec_b[0], cat);
  // layer 2 (64 -> 64)
  ec_layer64<<<dim3(1024, 8), 256, 0, stream>>>(cat, 0, idxbuf, ec_w[1], ec_s[1], ec_b[1], cat, 64);
  // layer 3 (64 -> 64)
  ec_layer64<<<dim3(1024, 8), 256, 0, stream>>>(cat, 64, idxbuf, ec_w[2], ec_s[2], ec_b[2], cat, 128);
  // layer 4 (64 -> 128), two 64-output halves (outputs independent -> exact)
  ec_layer64<<<dim3(1024, 8), 256, 0, stream>>>(cat, 128, idxbuf, ec_w[3], ec_s[3], ec_b[3], cat, 192);
  ec_layer64<<<dim3(1024, 8), 256, 0, stream>>>(cat, 128, idxbuf, ec_w[3] + 64 * 128,
                                                ec_s[3] + 64, ec_b[3] + 64, cat, 256);

  local_gemm<<<dim3(8, 256), 256, 0, stream>>>(cat, local_w, local_s, local_b, pv, pi);
  final_reduce<<<dim3(32), 256, 0, stream>>>(pv, pi, glob, oidx);
  dense_wave<1024, 512><<<dim3(1024), 256, 0, stream>>>(glob, g_w0, g_s0, g_b0, hbuf);
  dense_wave<512, 256><<<dim3(512), 256, 0, stream>>>(hbuf, g_w1, g_s1, g_b1, outv);
}

// Round 7
// 1779.947 us; speedup vs baseline: 1.2946x; 1.1539x over previous
//
#include <hip/hip_runtime.h>
#include <hip/hip_bf16.h>

namespace {
constexpr int B = 8;
constexpr int N = 4096;
constexpr int KNN = 20;
constexpr int NSEG = 4;
constexpr int SEGLEN = N / NSEG;   // 1024
constexpr int CAP = 24;
constexpr int SLOTS = NSEG * CAP;  // 96

// workspace layout (bytes)
constexpr size_t OFF_IDX  = 0;                          // int [B][N][KNN]
constexpr size_t SZ_IDX   = (size_t)B * N * KNN * 4;
constexpr size_t OFF_T    = OFF_IDX + SZ_IDX;           // knn scratch region
constexpr size_t SZ_T     = (size_t)B * N * 128 * 4;
constexpr size_t OFF_CAT  = OFF_T + SZ_T;               // float [B][N][320]
constexpr size_t SZ_CAT   = (size_t)B * N * 320 * 4;
constexpr size_t OFF_PV   = OFF_CAT + SZ_CAT;           // float [B][1024][32]
constexpr size_t SZ_PV    = (size_t)B * 1024 * 32 * 4;
constexpr size_t OFF_PI   = OFF_PV + SZ_PV;             // int   [B][1024][32]
constexpr size_t OFF_GLOB = OFF_PI + SZ_PV;             // float [B][1024]
constexpr size_t OFF_H    = OFF_GLOB + (size_t)B * 1024 * 4;  // float [B][512]
// knn scratch overlaid on T + head of CAT (dead once merge completes):
constexpr size_t OFF_LD   = OFF_T;                      // float [B*N][SLOTS]
constexpr size_t SZ_LD    = (size_t)B * N * SLOTS * 4;
constexpr size_t OFF_LJ   = OFF_LD + SZ_LD;             // int   [B*N][SLOTS]
constexpr size_t OFF_CNT  = OFF_LJ + SZ_LD;             // int   [B*N][NSEG]
}  // namespace

typedef float v2f __attribute__((ext_vector_type(2)));

// Non-contractable fp32 ops: bit-exact match to np's mul-then-add serial loops.
__device__ __forceinline__ float mulrn(float a, float b) {
#pragma clang fp contract(off)
  return a * b;
}
__device__ __forceinline__ float addrn(float a, float b) {
#pragma clang fp contract(off)
  return a + b;
}
__device__ __forceinline__ float subrn(float a, float b) {
#pragma clang fp contract(off)
  return a - b;
}
// Packed (v_pk_mul_f32 / v_pk_add_f32): per-element IEEE rn == scalar ops.
__device__ __forceinline__ v2f mulrn2(v2f a, v2f b) {
#pragma clang fp contract(off)
  return a * b;
}
__device__ __forceinline__ v2f addrn2(v2f a, v2f b) {
#pragma clang fp contract(off)
  return a + b;
}

// ---------------------------------------------------------------------------
// kNN: per-thread scan of one row-segment keeping sorted top-20 distances,
// then recovery pass collects (d, j) with d <= theta in ascending-j order.
// Distances for (j, j+1) computed packed; checks remain scalar in j order.
// ---------------------------------------------------------------------------
__global__ __launch_bounds__(256) void knn_scan(
    const float* __restrict__ pts,
    float* __restrict__ listd, int* __restrict__ listj, int* __restrict__ counts) {
  __shared__ float4 sp[N];  // 64 KB: (x, y, z, sq)
  const int b = blockIdx.y;
  const int tid = threadIdx.x;
  const float* px = pts + (size_t)b * 3 * N;
  for (int i = tid; i < N; i += 256) {
    const float x = px[i];
    const float y = px[N + i];
    const float z = px[2 * N + i];
    const float sq = addrn(addrn(mulrn(x, x), mulrn(y, y)), mulrn(z, z));
    sp[i] = make_float4(x, y, z, sq);
  }
  __syncthreads();
  const int row = blockIdx.x * 64 + (tid & 63);
  const int seg = tid >> 6;
  const float4 q = sp[row];
  float ds[KNN];
#pragma unroll
  for (int t = 0; t < KNN; ++t) ds[t] = 3.0e38f;
  const int j0 = seg * SEGLEN;
#pragma unroll 2
  for (int jj = 0; jj < SEGLEN; jj += 2) {
    const float4 c0 = sp[j0 + jj];
    const float4 c1 = sp[j0 + jj + 1];
    v2f t0 = mulrn2((v2f){q.x, q.x}, (v2f){c0.x, c1.x});
    t0 = addrn2(t0, mulrn2((v2f){q.y, q.y}, (v2f){c0.y, c1.y}));
    t0 = addrn2(t0, mulrn2((v2f){q.z, q.z}, (v2f){c0.z, c1.z}));
    v2f d2 = addrn2((v2f){q.w, q.w}, (v2f){c0.w, c1.w});
    d2 = d2 - mulrn2((v2f){2.0f, 2.0f}, t0);  // elementwise sub, rn
#pragma unroll
    for (int u = 0; u < 2; ++u) {
      const float d = u ? d2.y : d2.x;
      if (d < ds[KNN - 1]) {
        float cur = d;
#pragma unroll
        for (int t = 0; t < KNN; ++t) {
          const float lo = fminf(cur, ds[t]);
          cur = fmaxf(cur, ds[t]);
          ds[t] = lo;
        }
      }
    }
  }
  const float th = ds[KNN - 1];
  const int rbase = (b * N + row) * NSEG + seg;
  float* ld = listd + (size_t)(b * N + row) * SLOTS + seg * CAP;
  int* lj = listj + (size_t)(b * N + row) * SLOTS + seg * CAP;
  int cnt = 0;
#pragma unroll 2
  for (int jj = 0; jj < SEGLEN; jj += 2) {
    const float4 c0 = sp[j0 + jj];
    const float4 c1 = sp[j0 + jj + 1];
    v2f t0 = mulrn2((v2f){q.x, q.x}, (v2f){c0.x, c1.x});
    t0 = addrn2(t0, mulrn2((v2f){q.y, q.y}, (v2f){c0.y, c1.y}));
    t0 = addrn2(t0, mulrn2((v2f){q.z, q.z}, (v2f){c0.z, c1.z}));
    v2f d2 = addrn2((v2f){q.w, q.w}, (v2f){c0.w, c1.w});
    d2 = d2 - mulrn2((v2f){2.0f, 2.0f}, t0);
#pragma unroll
    for (int u = 0; u < 2; ++u) {
      const float d = u ? d2.y : d2.x;
      if (d <= th && cnt < CAP) {
        ld[cnt] = d;
        lj[cnt] = j0 + jj + u;
        ++cnt;
      }
    }
  }
  counts[rbase] = cnt;
}

// Merge: per row, select 20 lexicographically-smallest (dist, j) from <=96
// candidates via monotone uint64 keys.
__global__ __launch_bounds__(64) void knn_merge(
    const float* __restrict__ listd, const int* __restrict__ listj,
    const int* __restrict__ counts, int* __restrict__ idxout) {
  __shared__ unsigned long long keys[64][SLOTS + 1];  // 49,664 B
  const int r0 = blockIdx.x * 64;
  const int t = threadIdx.x;
  for (int i = t; i < 64 * SLOTS; i += 64) {
    const int rr = i / SLOTS;
    const int sl = i % SLOTS;
    const int seg = sl / CAP;
    const int e = sl % CAP;
    const int row = r0 + rr;
    unsigned long long key = 0xFFFFFFFE00000000ULL | (unsigned)row;  // fallback: self
    if (e < counts[row * NSEG + seg]) {
      const float d = listd[(size_t)row * SLOTS + sl];
      unsigned ub = __float_as_uint(d);
      ub ^= (ub & 0x80000000u) ? 0xFFFFFFFFu : 0x80000000u;
      key = ((unsigned long long)ub << 32) | (unsigned)listj[(size_t)row * SLOTS + sl];
    }
    keys[rr][sl] = key;
  }
  __syncthreads();
  int* outp = idxout + (size_t)(r0 + t) * KNN;
  for (int sel = 0; sel < KNN; ++sel) {
    unsigned long long best = ~0ULL;
    int bs = 0;
#pragma unroll 8
    for (int sl = 0; sl < SLOTS; ++sl) {
      const unsigned long long k2 = keys[t][sl];
      if (k2 < best) { best = k2; bs = sl; }
    }
    keys[t][bs] = ~0ULL;
    outp[sel] = (int)(best & 0xFFFFFFFFu);
  }
}

// ---------------------------------------------------------------------------
// EdgeConv, BIT-EXACT serial semantics per (o, n, k):
//   y = sum_c W[o,c]*ctr[c]  (prefix P)  then  += W[o,64+c]*(nb[c]-ctr[c]).
// ---------------------------------------------------------------------------

// Layer 1 (cin=3): wave per point, lane = output o.
__global__ __launch_bounds__(256) void ec_layer1(
    const float* __restrict__ pts, const int* __restrict__ idx,
    const float* __restrict__ w, const float* __restrict__ s,
    const float* __restrict__ bi, float* __restrict__ cat) {
  const int b = blockIdx.y;
  const int n = blockIdx.x * 4 + (threadIdx.x >> 6);
  const int o = threadIdx.x & 63;
  const float* p = pts + (size_t)b * 3 * N;
  const float xix = p[n], xiy = p[N + n], xiz = p[2 * N + n];
  const float* wr = w + o * 6;
  const float w0 = wr[0], w1 = wr[1], w2 = wr[2], w3 = wr[3], w4 = wr[4], w5 = wr[5];
  float P = mulrn(w0, xix);
  P = addrn(P, mulrn(w1, xiy));
  P = addrn(P, mulrn(w2, xiz));
  const float so = s[o], bo = bi[o];
  const int* ip = idx + ((size_t)b * N + n) * KNN;
  float m = 0.0f;
#pragma unroll 4
  for (int k = 0; k < KNN; ++k) {
    int j = ip[k];
    if ((unsigned)j >= (unsigned)N) j = n;
    const float ex = subrn(p[j], xix);
    const float ey = subrn(p[N + j], xiy);
    const float ez = subrn(p[2 * N + j], xiz);
    float acc = addrn(P, mulrn(w3, ex));
    acc = addrn(acc, mulrn(w4, ey));
    acc = addrn(acc, mulrn(w5, ez));
    m = fmaxf(m, addrn(mulrn(so, acc), bo));
  }
  cat[((size_t)b * N + n) * 320 + o] = m;
}

// 64-in/64-out EdgeConv layer, prefix fused, NEIGHBOR-PAIR packed (v_pk).
__global__ __launch_bounds__(256) void ec_layer64(
    const float* __restrict__ cat, int inoff, const int* __restrict__ idx,
    const float* __restrict__ w, const float* __restrict__ s,
    const float* __restrict__ bi, float* __restrict__ catout, int outoff) {
  __shared__ float wst[64][130];  // 33,280 B; pad 130 -> 2-way (free) reads
  __shared__ v2f ebuf[4][64];     // 2 KB: per-wave packed e vectors (2 nbrs)
  for (int l = threadIdx.x; l < 64 * 128; l += 256) {
    wst[l >> 7][l & 127] = w[l];
  }
  __syncthreads();
  const int b = blockIdx.y;
  const int wv = threadIdx.x >> 6;
  const int n = blockIdx.x * 4 + wv;
  const int o = threadIdx.x & 63;
  float wreg[64];
#pragma unroll
  for (int c = 0; c < 64; ++c) wreg[c] = wst[o][64 + c];
  const float xi = cat[((size_t)b * N + n) * 320 + inoff + o];
  v2f* eb = &ebuf[wv][0];
  // prefix P = serial sum_{c<64} W[o][c] * x_i[c]; x_i staged via ebuf.x
  eb[o] = (v2f){xi, xi};
  float P;
  {
    const float4* e4 = (const float4*)eb;  // x of c, y of c, x of c+1, ...
    float4 v0 = e4[0];                     // (xi[0], xi[0], xi[1], xi[1])
    P = mulrn(wst[o][0], v0.x);
    P = addrn(P, mulrn(wst[o][1], v0.z));
#pragma unroll
    for (int c2 = 1; c2 < 32; ++c2) {
      const float4 v = e4[c2];
      P = addrn(P, mulrn(wst[o][2 * c2], v.x));
      P = addrn(P, mulrn(wst[o][2 * c2 + 1], v.z));
    }
  }
  const float so = s[o], bo = bi[o];
  const int* ip = idx + ((size_t)b * N + n) * KNN;
  float m = 0.0f;
  for (int kp = 0; kp < KNN / 2; ++kp) {
    int j0 = ip[2 * kp];
    int j1 = ip[2 * kp + 1];
    if ((unsigned)j0 >= (unsigned)N) j0 = n;
    if ((unsigned)j1 >= (unsigned)N) j1 = n;
    const float xj0 = cat[((size_t)b * N + j0) * 320 + inoff + o];
    const float xj1 = cat[((size_t)b * N + j1) * 320 + inoff + o];
    eb[o] = (v2f){subrn(xj0, xi), subrn(xj1, xi)};  // intra-wave, lgkmcnt-ordered
    v2f acc = (v2f){P, P};
    const float4* e4 = (const float4*)eb;  // 2 c's x 2 neighbors per read
#pragma unroll
    for (int c2 = 0; c2 < 32; ++c2) {
      const float4 v = e4[c2];  // broadcast (all lanes same addr)
      acc = addrn2(acc, mulrn2((v2f){wreg[2 * c2], wreg[2 * c2]}, (v2f){v.x, v.y}));
      acc = addrn2(acc, mulrn2((v2f){wreg[2 * c2 + 1], wreg[2 * c2 + 1]}, (v2f){v.z, v.w}));
    }
    const v2f vv = addrn2(mulrn2((v2f){so, so}, acc), (v2f){bo, bo});
    m = fmaxf(m, fmaxf(vv.x, vv.y));
  }
  catout[((size_t)b * N + n) * 320 + outoff + o] = m;
}

// ---------------------------------------------------------------------------
// Local layer: loc[o][n] = relu(s*<W[o,:],cat[n,:]>+b), serial ascending c,
// OUTPUT-PAIR packed (v_pk_mul/add: per-element rn == scalar -> bit-exact).
// Outputs per thread: h*8 + f (f=0..7, 4 v2f pairs); points: g + 16e.
// Register-prefetch double-buffered staging.
// ---------------------------------------------------------------------------
__global__ __launch_bounds__(256) void local_gemm(
    const float* __restrict__ cat, const float* __restrict__ w,
    const float* __restrict__ s, const float* __restrict__ bi,
    float* __restrict__ pval, int* __restrict__ pidx) {
  constexpr int KC = 32;
  constexpr int XP = 129;  // odd -> conflict-free b32 frag reads
  constexpr int WP = 130;  // even -> 8B-aligned b64 frag reads, free stores
  __shared__ float smem[KC * XP + KC * WP];  // 33,152 B
  float* xs = smem;
  float* wsd = smem + KC * XP;
  const int t = threadIdx.x;
  const int q0 = blockIdx.x * 128;
  const int ptile = blockIdx.y;
  const size_t pt0 = (size_t)ptile * 128;
  const int g = t & 15;   // point frag
  const int h = t >> 4;   // output frag: outputs q0 + h*8 + f
  v2f acc2[4][8];
#pragma unroll
  for (int f2 = 0; f2 < 4; ++f2)
#pragma unroll
    for (int e = 0; e < 8; ++e) acc2[f2][e] = (v2f){0.f, 0.f};

  const int lk = t & 31;
  const int lp = t >> 5;
  const float* catp = cat + pt0 * 320 + lk;
  const float* wp = w + (size_t)q0 * 320 + lk;
  float rx[16], rw[16];
#pragma unroll
  for (int i = 0; i < 16; ++i) rx[i] = catp[(size_t)(lp + 8 * i) * 320];
#pragma unroll
  for (int i = 0; i < 16; ++i) rw[i] = wp[(size_t)(lp + 8 * i) * 320];

  for (int kc = 0; kc < 320; kc += KC) {
#pragma unroll
    for (int i = 0; i < 16; ++i) xs[lk * XP + lp + 8 * i] = rx[i];
#pragma unroll
    for (int i = 0; i < 16; ++i) wsd[lk * WP + lp + 8 * i] = rw[i];
    __syncthreads();
    if (kc + KC < 320) {  // prefetch next chunk into registers
      const int ko = kc + KC;
#pragma unroll
      for (int i = 0; i < 16; ++i) rx[i] = catp[(size_t)(lp + 8 * i) * 320 + ko];
#pragma unroll
      for (int i = 0; i < 16; ++i) rw[i] = wp[(size_t)(lp + 8 * i) * 320 + ko];
    }
#pragma unroll
    for (int k = 0; k < KC; ++k) {
      float xf[8];
      v2f wf2[4];
#pragma unroll
      for (int e = 0; e < 8; ++e) xf[e] = xs[k * XP + g + 16 * e];
#pragma unroll
      for (int f2 = 0; f2 < 4; ++f2)
        wf2[f2] = *(const v2f*)&wsd[k * WP + h * 8 + 2 * f2];
#pragma unroll
      for (int f2 = 0; f2 < 4; ++f2)
#pragma unroll
        for (int e = 0; e < 8; ++e)
          acc2[f2][e] = addrn2(acc2[f2][e], mulrn2(wf2[f2], (v2f){xf[e], xf[e]}));
    }
    __syncthreads();
  }
  // epilogue: relu(s*acc+b) (mul-then-add), per-thread argmax over 8 points
  // (e ascending -> ascending point idx within thread -> first occurrence).
  const int bb = ptile >> 5;
  const int blk = ptile & 31;
  float mv[8];
  int mi[8];
#pragma unroll
  for (int f = 0; f < 8; ++f) {
    const int cl = h * 8 + f;
    const float sc = s[q0 + cl];
    const float bc = bi[q0 + cl];
    mv[f] = -1.f;
    mi[f] = 0;
#pragma unroll
    for (int e = 0; e < 8; ++e) {
      const float a = (f & 1) ? acc2[f >> 1][e].y : acc2[f >> 1][e].x;
      const float v = fmaxf(addrn(mulrn(sc, a), bc), 0.f);
      if (v > mv[f]) { mv[f] = v; mi[f] = g + 16 * e; }
    }
  }
  __syncthreads();
  float* smv = smem;
  int* smi = (int*)(smem + 16 * 132);
#pragma unroll
  for (int f = 0; f < 8; ++f) {
    smv[g * 132 + h * 8 + f] = mv[f];
    smi[g * 132 + h * 8 + f] = mi[f];
  }
  __syncthreads();
  if (t < 128) {
    float best = smv[t];
    int bidx = smi[t];
    for (int gg = 1; gg < 16; ++gg) {
      const float v = smv[gg * 132 + t];
      const int vi = smi[gg * 132 + t];
      // candidates g-interleaved: ties resolve to SMALLEST point idx
      if (v > best || (v == best && vi < bidx)) { best = v; bidx = vi; }
    }
    const int n_l = blk * 128 + bidx;
    const size_t po = ((size_t)bb * 1024 + q0 + t) * 32 + blk;
    pval[po] = best;
    pidx[po] = n_l;
  }
}

__global__ __launch_bounds__(256) void final_reduce(
    const float* __restrict__ pval, const int* __restrict__ pidx,
    float* __restrict__ glob, float* __restrict__ oidx) {
  const int o = blockIdx.x * 256 + threadIdx.x;  // 8192 = B*1024
  const float* pv = pval + (size_t)o * 32;
  const int* pi = pidx + (size_t)o * 32;
  float best = pv[0];
  int bi = pi[0];
  for (int k = 1; k < 32; ++k) {
    const float v = pv[k];
    // tiles are ascending disjoint point ranges: strict > = first occurrence
    if (v > best) { best = v; bi = pi[k]; }
  }
  glob[o] = best;
  oidx[o] = (float)bi;
}

template <int KIN, int OUTS>
__global__ __launch_bounds__(256) void dense_wave(
    const float* __restrict__ in, const float* __restrict__ w,
    const float* __restrict__ s, const float* __restrict__ bi,
    float* __restrict__ out) {
  const int wid = (blockIdx.x * 256 + threadIdx.x) >> 6;
  const int lane = threadIdx.x & 63;
  const int b = wid / OUTS;
  const int o = wid % OUTS;
  const float* ip = in + (size_t)b * KIN;
  const float* wr = w + (size_t)o * KIN;
  float acc = 0.f;
  for (int k = lane; k < KIN; k += 64) acc = fmaf(wr[k], ip[k], acc);
#pragma unroll
  for (int off = 32; off; off >>= 1) acc += __shfl_down(acc, off);
  if (lane == 0) out[(size_t)b * OUTS + o] = fmaxf(fmaf(s[o], acc, bi[o]), 0.f);
}

extern "C" void kernel_launch(void* const* d_in, const int* in_sizes, int n_in,
                              void* d_out, int out_size, void* d_ws, size_t ws_size,
                              hipStream_t stream) {
  (void)in_sizes; (void)n_in; (void)out_size; (void)ws_size;
  const float* pts = (const float*)d_in[0];
  const float* ec_w[4] = {(const float*)d_in[1], (const float*)d_in[4],
                          (const float*)d_in[7], (const float*)d_in[10]};
  const float* ec_s[4] = {(const float*)d_in[2], (const float*)d_in[5],
                          (const float*)d_in[8], (const float*)d_in[11]};
  const float* ec_b[4] = {(const float*)d_in[3], (const float*)d_in[6],
                          (const float*)d_in[9], (const float*)d_in[12]};
  const float* local_w = (const float*)d_in[13];
  const float* local_s = (const float*)d_in[14];
  const float* local_b = (const float*)d_in[15];
  const float* g_w0 = (const float*)d_in[16];
  const float* g_s0 = (const float*)d_in[17];
  const float* g_b0 = (const float*)d_in[18];
  const float* g_w1 = (const float*)d_in[19];
  const float* g_s1 = (const float*)d_in[20];
  const float* g_b1 = (const float*)d_in[21];

  char* ws = (char*)d_ws;
  int* idxbuf = (int*)(ws + OFF_IDX);
  float* cat = (float*)(ws + OFF_CAT);
  float* pv = (float*)(ws + OFF_PV);
  int* pi = (int*)(ws + OFF_PI);
  float* glob = (float*)(ws + OFF_GLOB);
  float* hbuf = (float*)(ws + OFF_H);
  float* listd = (float*)(ws + OFF_LD);
  int* listj = (int*)(ws + OFF_LJ);
  int* counts = (int*)(ws + OFF_CNT);
  float* outv = (float*)d_out;   // [8][256]  fp32
  float* oidx = outv + 2048;     // [8][1024] fp32 (indices as floats)

  knn_scan<<<dim3(64, 8), 256, 0, stream>>>(pts, listd, listj, counts);
  knn_merge<<<dim3(512), 64, 0, stream>>>(listd, listj, counts, idxbuf);

  // layer 1 (3 -> 64)
  ec_layer1<<<dim3(1024, 8), 256, 0, stream>>>(pts, idxbuf, ec_w[0], ec_s[0], ec_b[0], cat);
  // layer 2 (64 -> 64)
  ec_layer64<<<dim3(1024, 8), 256, 0, stream>>>(cat, 0, idxbuf, ec_w[1], ec_s[1], ec_b[1], cat, 64);
  // layer 3 (64 -> 64)
  ec_layer64<<<dim3(1024, 8), 256, 0, stream>>>(cat, 64, idxbuf, ec_w[2], ec_s[2], ec_b[2], cat, 128);
  // layer 4 (64 -> 128), two 64-output halves (outputs independent -> exact)
  ec_layer64<<<dim3(1024, 8), 256, 0, stream>>>(cat, 128, idxbuf, ec_w[3], ec_s[3], ec_b[3], cat, 192);
  ec_layer64<<<dim3(1024, 8), 256, 0, stream>>>(cat, 128, idxbuf, ec_w[3] + 64 * 128,
                                                ec_s[3] + 64, ec_b[3] + 64, cat, 256);

  local_gemm<<<dim3(8, 256), 256, 0, stream>>>(cat, local_w, local_s, local_b, pv, pi);
  final_reduce<<<dim3(32), 256, 0, stream>>>(pv, pi, glob, oidx);
  dense_wave<1024, 512><<<dim3(1024), 256, 0, stream>>>(glob, g_w0, g_s0, g_b0, hbuf);
  dense_wave<512, 256><<<dim3(512), 256, 0, stream>>>(hbuf, g_w1, g_s1, g_b1, outv);
}